// Round 7
// baseline (658.437 us; speedup 1.0000x reference)
//
#include <hip/hip_runtime.h>
#include <math.h>

typedef __attribute__((ext_vector_type(8))) short s16x8;
typedef __attribute__((ext_vector_type(4))) float f32x4;

#define MFMA(a,b,c) __builtin_amdgcn_mfma_f32_16x16x32_bf16((a),(b),(c),0,0,0)

__device__ __forceinline__ unsigned short f2bf(float f){
    unsigned u = __builtin_bit_cast(unsigned, f);
    u += 0x7FFFu + ((u >> 16) & 1u);
    return (unsigned short)(u >> 16);
}
__device__ __forceinline__ float bf2f(unsigned short u){
    return __builtin_bit_cast(float, ((unsigned)u) << 16);
}
__device__ __forceinline__ float4 fma4(float s, float4 a, float4 c){
    c.x = fmaf(s, a.x, c.x); c.y = fmaf(s, a.y, c.y);
    c.z = fmaf(s, a.z, c.z); c.w = fmaf(s, a.w, c.w);
    return c;
}
__device__ __forceinline__ unsigned pk_bf16(float lo, float hi){
    return (unsigned)f2bf(lo) | ((unsigned)f2bf(hi) << 16);
}
__device__ __forceinline__ void gld_lds16(const void* g, void* l){
    __builtin_amdgcn_global_load_lds(
        (const __attribute__((address_space(1))) void*)g,
        (__attribute__((address_space(3))) void*)l, 16, 0, 0);
}

// ---------------------------------------------------------------------------
// QKV projection: qkv = query @ in_w^T + in_b, emitted as:
//   qs [48][1024][64] bf16  (q * 0.125)
//   kb [48][1024][64] bf16
//   vt [48][64][1024] bf16  (transposed)
// ---------------------------------------------------------------------------
__global__ __launch_bounds__(256) void gemm_qkv(
    const float* __restrict__ X, const float* __restrict__ W,
    const float* __restrict__ bvec,
    unsigned short* __restrict__ qs,
    unsigned short* __restrict__ kb,
    unsigned short* __restrict__ vtb)
{
    __shared__ __align__(16) unsigned short Al[128*64];
    __shared__ __align__(16) unsigned short Bl[128*64];
    const int tid = threadIdx.x;
    const int m0 = blockIdx.y*128, n0 = blockIdx.x*128;
    const int w = tid>>6, lane = tid&63, g = lane>>4, cc = lane&15;
    const int srow = tid>>1, kh = (tid&1)*32;
    const int arow_base = (w>>1)*64, brow_base = (w&1)*64;

    f32x4 acc[4][4];
#pragma unroll
    for (int i=0;i<4;i++)
#pragma unroll
        for (int j=0;j<4;j++) acc[i][j] = (f32x4){0.f,0.f,0.f,0.f};

    const float* xp = X + (size_t)(m0+srow)*768 + kh;
    const float* wp = W + (size_t)(n0+srow)*768 + kh;

    for (int kt = 0; kt < 768; kt += 64) {
        float4 xv[8], wv[8];
#pragma unroll
        for (int i=0;i<8;i++){
            xv[i] = *(const float4*)(xp + kt + i*4);
            wv[i] = *(const float4*)(wp + kt + i*4);
        }
        __syncthreads();
#pragma unroll
        for (int q=0;q<4;q++){
            alignas(16) unsigned short ta[8], tb[8];
            float4 a0=xv[2*q], a1=xv[2*q+1], b0=wv[2*q], b1=wv[2*q+1];
            ta[0]=f2bf(a0.x); ta[1]=f2bf(a0.y); ta[2]=f2bf(a0.z); ta[3]=f2bf(a0.w);
            ta[4]=f2bf(a1.x); ta[5]=f2bf(a1.y); ta[6]=f2bf(a1.z); ta[7]=f2bf(a1.w);
            tb[0]=f2bf(b0.x); tb[1]=f2bf(b0.y); tb[2]=f2bf(b0.z); tb[3]=f2bf(b0.w);
            tb[4]=f2bf(b1.x); tb[5]=f2bf(b1.y); tb[6]=f2bf(b1.z); tb[7]=f2bf(b1.w);
            const int gr = (kh>>3) + q;
            const int sw = ((gr ^ (srow&7))<<3);
            *(s16x8*)&Al[srow*64 + sw] = *(const s16x8*)ta;
            *(s16x8*)&Bl[srow*64 + sw] = *(const s16x8*)tb;
        }
        __syncthreads();
#pragma unroll
        for (int ks=0;ks<2;ks++){
            s16x8 af[4], bfr[4];
#pragma unroll
            for (int i=0;i<4;i++){
                const int ra = arow_base + i*16 + cc;
                const int rb = brow_base + i*16 + cc;
                af[i]  = *(const s16x8*)&Al[ra*64 + (((ks*4+g) ^ (ra&7))<<3)];
                bfr[i] = *(const s16x8*)&Bl[rb*64 + (((ks*4+g) ^ (rb&7))<<3)];
            }
#pragma unroll
            for (int i=0;i<4;i++)
#pragma unroll
                for (int j=0;j<4;j++)
                    acc[i][j] = MFMA(af[i], bfr[j], acc[i][j]);
        }
    }

    const int region = blockIdx.x / 6;   // 0:q 1:k 2:v
#pragma unroll
    for (int j=0;j<4;j++){
        const int n = n0 + brow_base + j*16 + cc;
        const float bb = bvec[n];
        const int nn = n - region*768;
        const int h = nn >> 6, d = nn & 63;
        if (region == 0){
#pragma unroll
            for (int i=0;i<4;i++){
                const int m = m0 + arow_base + i*16 + g*4;
                const int bq = m >> 10, t = m & 1023;
                unsigned short* dst = qs + ((size_t)(bq*12+h)*1024 + t)*64 + d;
#pragma unroll
                for (int r=0;r<4;r++)
                    dst[(size_t)r*64] = f2bf((acc[i][j][r] + bb)*0.125f);
            }
        } else if (region == 1){
#pragma unroll
            for (int i=0;i<4;i++){
                const int m = m0 + arow_base + i*16 + g*4;
                const int bq = m >> 10, t = m & 1023;
                unsigned short* dst = kb + ((size_t)(bq*12+h)*1024 + t)*64 + d;
#pragma unroll
                for (int r=0;r<4;r++)
                    dst[(size_t)r*64] = f2bf(acc[i][j][r] + bb);
            }
        } else {
#pragma unroll
            for (int i=0;i<4;i++){
                const int m = m0 + arow_base + i*16 + g*4;
                const int bq = m >> 10, t = m & 1023;
                ushort4 pk;
                pk.x = f2bf(acc[i][j][0] + bb);
                pk.y = f2bf(acc[i][j][1] + bb);
                pk.z = f2bf(acc[i][j][2] + bb);
                pk.w = f2bf(acc[i][j][3] + bb);
                *(ushort4*)&vtb[((size_t)(bq*12+h)*64 + d)*1024 + t] = pk;
            }
        }
    }
}

// ---------------------------------------------------------------------------
// Generic x @ W^T + b (f32 in/out) for the output projection.
// ---------------------------------------------------------------------------
__global__ __launch_bounds__(256) void gemm_mfma(
    const float* __restrict__ X, const float* __restrict__ W,
    const float* __restrict__ bvec, float* __restrict__ out,
    int N, int K)
{
    __shared__ __align__(16) unsigned short Al[128*64];
    __shared__ __align__(16) unsigned short Bl[128*64];
    const int tid = threadIdx.x;
    const int m0 = blockIdx.y*128, n0 = blockIdx.x*128;
    const int w = tid>>6, lane = tid&63, g = lane>>4, cc = lane&15;
    const int srow = tid>>1, kh = (tid&1)*32;
    const int arow_base = (w>>1)*64, brow_base = (w&1)*64;

    f32x4 acc[4][4];
#pragma unroll
    for (int i=0;i<4;i++)
#pragma unroll
        for (int j=0;j<4;j++) acc[i][j] = (f32x4){0.f,0.f,0.f,0.f};

    const float* xp = X + (size_t)(m0+srow)*K + kh;
    const float* wp = W + (size_t)(n0+srow)*K + kh;

    for (int kt = 0; kt < K; kt += 64) {
        float4 xv[8], wv[8];
#pragma unroll
        for (int i=0;i<8;i++){
            xv[i] = *(const float4*)(xp + kt + i*4);
            wv[i] = *(const float4*)(wp + kt + i*4);
        }
        __syncthreads();
#pragma unroll
        for (int q=0;q<4;q++){
            alignas(16) unsigned short ta[8], tb[8];
            float4 a0=xv[2*q], a1=xv[2*q+1], b0=wv[2*q], b1=wv[2*q+1];
            ta[0]=f2bf(a0.x); ta[1]=f2bf(a0.y); ta[2]=f2bf(a0.z); ta[3]=f2bf(a0.w);
            ta[4]=f2bf(a1.x); ta[5]=f2bf(a1.y); ta[6]=f2bf(a1.z); ta[7]=f2bf(a1.w);
            tb[0]=f2bf(b0.x); tb[1]=f2bf(b0.y); tb[2]=f2bf(b0.z); tb[3]=f2bf(b0.w);
            tb[4]=f2bf(b1.x); tb[5]=f2bf(b1.y); tb[6]=f2bf(b1.z); tb[7]=f2bf(b1.w);
            const int gr = (kh>>3) + q;
            const int sw = ((gr ^ (srow&7))<<3);
            *(s16x8*)&Al[srow*64 + sw] = *(const s16x8*)ta;
            *(s16x8*)&Bl[srow*64 + sw] = *(const s16x8*)tb;
        }
        __syncthreads();
#pragma unroll
        for (int ks=0;ks<2;ks++){
            s16x8 af[4], bfr[4];
#pragma unroll
            for (int i=0;i<4;i++){
                const int ra = arow_base + i*16 + cc;
                const int rb = brow_base + i*16 + cc;
                af[i]  = *(const s16x8*)&Al[ra*64 + (((ks*4+g) ^ (ra&7))<<3)];
                bfr[i] = *(const s16x8*)&Bl[rb*64 + (((ks*4+g) ^ (rb&7))<<3)];
            }
#pragma unroll
            for (int i=0;i<4;i++)
#pragma unroll
                for (int j=0;j<4;j++)
                    acc[i][j] = MFMA(af[i], bfr[j], acc[i][j]);
        }
    }
#pragma unroll
    for (int j=0;j<4;j++){
        const int n = n0 + brow_base + j*16 + cc;
        const float bb = bvec[n];
#pragma unroll
        for (int i=0;i<4;i++){
            const int mb = m0 + arow_base + i*16 + g*4;
#pragma unroll
            for (int r=0;r<4;r++)
                out[(size_t)(mb+r)*N + n] = acc[i][j][r] + bb;
        }
    }
}

// ---------------------------------------------------------------------------
// Flash attention, 1 wave / 16 q-rows per block, full DMA streaming.
// s-chunk = 128: kdyn visited 512 B per (t,r) row (DRAM-friendly), staged via
// global_load_lds into double-buffered LDS (kd 32 + bias 8 + K 16 = 56 DMA
// per chunk, counted s_waitcnt vmcnt(56)). V/mask preloaded to regs BEFORE the
// stage so no compiler vmcnt drains the pipeline. Zero barriers.
// Swizzle: granule gl' = (gl&~7)|((gl&7)^(t&7)) applied on the global source,
// same XOR on the LDS read (both-sides rule).
// ---------------------------------------------------------------------------
__global__ __launch_bounds__(64, 1) void attn_mfma(
    const unsigned short* __restrict__ qs,   // [48][1024][64] bf16 (q*0.125)
    const unsigned short* __restrict__ kbf,  // [48][1024][64] bf16
    const unsigned short* __restrict__ vtf,  // [48][64][1024] bf16
    const float* __restrict__ kdyn,          // [48*1024][4][1024]
    const int*   __restrict__ kpm,           // [4][1024]
    const float* __restrict__ bias,          // [48][1024][1024]
    const float* __restrict__ red_w,         // [4][64]
    const float* __restrict__ red_b,         // [4]
    float* __restrict__ o)                   // [4096][768]
{
    __shared__ __align__(16) float kdL[2][8192];           // 2 x 32 KB: row rr=t*4+r (128 f32/row)
    __shared__ __align__(16) float bL[2][2048];            // 2 x  8 KB: row t (128 f32/row)
    __shared__ __align__(16) unsigned short Klds[2][8192]; // 2 x 16 KB: row s (64 us/row)

    const int lane = threadIdx.x & 63;
    const int bh = blockIdx.x, qt = blockIdx.y;   // bh fastest: same-bh -> same XCD
    const int b = bh / 12, h = bh % 12;
    const int t0 = qt*16;
    const int g = lane>>4, cc = lane&15;
    const int tq = t0 + cc;                        // lane's q row (within b,h)

    // ---- Q fragments (B-operand): Q[q=cc][d = 32ks+8g+e]
    const unsigned short* qrow = qs + ((size_t)bh*1024 + tq)*64;
    s16x8 qf[2];
    qf[0] = *(const s16x8*)(qrow + g*8);
    qf[1] = *(const s16x8*)(qrow + 32 + g*8);

    // ---- qred[r] for q=cc
    float qred[4];
    {
        float pr[4] = {0.f,0.f,0.f,0.f};
#pragma unroll
        for (int ks=0; ks<2; ks++){
#pragma unroll
            for (int r=0;r<4;r++){
                float4 w0 = *(const float4*)(red_w + r*64 + 32*ks + 8*g);
                float4 w1 = *(const float4*)(red_w + r*64 + 32*ks + 8*g + 4);
                pr[r] += bf2f((unsigned short)qf[ks][0])*w0.x + bf2f((unsigned short)qf[ks][1])*w0.y
                       + bf2f((unsigned short)qf[ks][2])*w0.z + bf2f((unsigned short)qf[ks][3])*w0.w
                       + bf2f((unsigned short)qf[ks][4])*w1.x + bf2f((unsigned short)qf[ks][5])*w1.y
                       + bf2f((unsigned short)qf[ks][6])*w1.z + bf2f((unsigned short)qf[ks][7])*w1.w;
            }
        }
#pragma unroll
        for (int r=0;r<4;r++){
            pr[r] += __shfl_xor(pr[r], 16);
            pr[r] += __shfl_xor(pr[r], 32);
            qred[r] = pr[r]*8.f + red_b[r];
        }
    }

    f32x4 accO[4];
#pragma unroll
    for (int i=0;i<4;i++) accO[i] = (f32x4){0.f,0.f,0.f,0.f};
    float m_ = -1e30f, l_ = 0.f;

    const unsigned short* kcb = kbf + (size_t)bh*1024*64;
    const unsigned short* vcb = vtf + ((size_t)bh*64 + cc)*1024;
    const int* mp = kpm + b*1024 + 4*g;
    const size_t kd_row = (size_t)(bh*1024 + t0);

    // staging lane geometry
    const int half = lane>>5, gl = lane&31;       // kd/bias: 2 rows/inst, 32 granules
    const int krow8 = lane>>3, kgd = lane&7;      // K: 8 rows/inst, 8 granules

    #define STAGE(buf_, c_) do {                                                  \
        const int s0_ = (c_)*128;                                                 \
        _Pragma("unroll")                                                         \
        for (int i_=0;i_<32;i_++){            /* kdyn: rows rr=2i+half */         \
            const int rr_ = 2*i_ + half;                                          \
            const int t_ = rr_>>2, r_ = rr_&3;                                    \
            const int gsw_ = (gl & 24) | ((gl&7) ^ (t_&7));                       \
            gld_lds16(kdyn + (kd_row + t_)*4096 + (size_t)r_*1024 + s0_ + gsw_*4, \
                      &kdL[buf_][i_*256]);                                        \
        }                                                                         \
        _Pragma("unroll")                                                         \
        for (int i_=0;i_<8;i_++){             /* bias: rows t=2i+half */          \
            const int t_ = 2*i_ + half;                                           \
            const int gsw_ = (gl & 24) | ((gl&7) ^ (t_&7));                       \
            gld_lds16(bias + (kd_row + t_)*1024 + s0_ + gsw_*4,                   \
                      &bL[buf_][i_*256]);                                         \
        }                                                                         \
        _Pragma("unroll")                                                         \
        for (int i_=0;i_<16;i_++){            /* K: rows s=i*8+krow8 */           \
            const int sr_ = i_*8 + krow8;                                         \
            gld_lds16(kcb + (size_t)(s0_ + sr_)*64 + ((kgd ^ (sr_&7))<<3),        \
                      &Klds[buf_][i_*512]);                                       \
        }                                                                         \
    } while(0)

    // ---- prologue: stage chunk 0
    STAGE(0, 0);

    const float NINF = -__builtin_inff();
    const int srcA = ((g&1)<<5) + cc;
    const int srcB = srcA + 16;
    const bool hi_half = (g>>1) != 0;

#pragma unroll 1
    for (int c = 0; c < 8; ++c) {
        const int buf = c & 1;
        const int cbase = c*128;

        // ---- V + mask register preloads for the whole chunk (BEFORE stage)
        s16x8 vfr[4][4];
        int4 mm[4][2];
#pragma unroll
        for (int sub=0;sub<4;sub++){
            const int s32 = cbase + sub*32;
#pragma unroll
            for (int dq=0;dq<4;dq++)
                vfr[sub][dq] = *(const s16x8*)(vcb + (size_t)dq*16*1024 + s32 + 8*g);
            mm[sub][0] = *(const int4*)(mp + s32);
            mm[sub][1] = *(const int4*)(mp + s32 + 16);
        }

        // ---- issue next chunk's 56 DMAs, then wait for THIS chunk (+V/mask)
        if (c < 7){
            STAGE(buf^1, c+1);
            asm volatile("s_waitcnt vmcnt(56)" ::: "memory");
        } else {
            asm volatile("s_waitcnt vmcnt(0)" ::: "memory");
        }
        __builtin_amdgcn_sched_barrier(0);

#pragma unroll
        for (int sub=0;sub<4;sub++){
            // ---- dyn tile from LDS (swizzled read): t=cc, s=16sq+4g+{0..3}
            float4 dyn[2];
#pragma unroll
            for (int sq=0;sq<2;sq++){
                const int slot = (sub*8 + ((4*sq + g) ^ (cc&7))) << 2;
                float4 dv = *(const float4*)&bL[buf][cc*128 + slot];
                dv = fma4(qred[0], *(const float4*)&kdL[buf][(cc*4+0)*128 + slot], dv);
                dv = fma4(qred[1], *(const float4*)&kdL[buf][(cc*4+1)*128 + slot], dv);
                dv = fma4(qred[2], *(const float4*)&kdL[buf][(cc*4+2)*128 + slot], dv);
                dv = fma4(qred[3], *(const float4*)&kdL[buf][(cc*4+3)*128 + slot], dv);
                const int4 m4 = mm[sub][sq];
                dv.x = m4.x ? NINF : dv.x;
                dv.y = m4.y ? NINF : dv.y;
                dv.z = m4.z ? NINF : dv.z;
                dv.w = m4.w ? NINF : dv.w;
                dyn[sq] = dv;
            }

            // ---- QK^T (swapped) from K-LDS: row = sub*32+16sq+cc
            f32x4 sc[2];
            __builtin_amdgcn_s_setprio(1);
#pragma unroll
            for (int sq=0;sq<2;sq++){
                const int rowk = sub*32 + 16*sq + cc;
                f32x4 z = (f32x4){0.f,0.f,0.f,0.f};
                s16x8 kf0 = *(const s16x8*)&Klds[buf][rowk*64 + (((0+g) ^ (cc&7))<<3)];
                s16x8 kf1 = *(const s16x8*)&Klds[buf][rowk*64 + (((4+g) ^ (cc&7))<<3)];
                z = MFMA(kf0, qf[0], z);
                z = MFMA(kf1, qf[1], z);
                sc[sq] = z;
            }
            __builtin_amdgcn_s_setprio(0);

            // ---- softmax (in-register; q=cc shared by 4 g-lanes)
            float v[8];
#pragma unroll
            for (int sq=0;sq<2;sq++){
                v[sq*4+0] = sc[sq][0] + dyn[sq].x;
                v[sq*4+1] = sc[sq][1] + dyn[sq].y;
                v[sq*4+2] = sc[sq][2] + dyn[sq].z;
                v[sq*4+3] = sc[sq][3] + dyn[sq].w;
            }
            float mx = v[0];
#pragma unroll
            for (int i=1;i<8;i++) mx = fmaxf(mx, v[i]);
            mx = fmaxf(mx, __shfl_xor(mx, 16));
            mx = fmaxf(mx, __shfl_xor(mx, 32));
            const float mn = fmaxf(m_, mx);
            float ps = 0.f;
#pragma unroll
            for (int i=0;i<8;i++){ v[i] = __expf(v[i]-mn); ps += v[i]; }
            ps += __shfl_xor(ps, 16);
            ps += __shfl_xor(ps, 32);
            const float scl = __expf(m_-mn);
            m_ = mn; l_ = l_*scl + ps;

            // ---- pack P, exchange -> PV A-fragment P[q=cc][s=8g+e]
            unsigned U[4] = { pk_bf16(v[0],v[1]), pk_bf16(v[2],v[3]),
                              pk_bf16(v[4],v[5]), pk_bf16(v[6],v[7]) };
            unsigned a0 = (unsigned)__shfl((int)U[0], srcA);
            unsigned a1 = (unsigned)__shfl((int)U[1], srcA);
            unsigned a2 = (unsigned)__shfl((int)U[2], srcA);
            unsigned a3 = (unsigned)__shfl((int)U[3], srcA);
            unsigned b0 = (unsigned)__shfl((int)U[0], srcB);
            unsigned b1 = (unsigned)__shfl((int)U[1], srcB);
            unsigned b2 = (unsigned)__shfl((int)U[2], srcB);
            unsigned b3 = (unsigned)__shfl((int)U[3], srcB);
            alignas(16) unsigned wv4[4] = { hi_half ? a2 : a0, hi_half ? a3 : a1,
                                            hi_half ? b2 : b0, hi_half ? b3 : b1 };
            s16x8 pa = *(const s16x8*)wv4;

            // ---- rescale accO (scl for q=4g+r lives at lane 16g + 4g+r)
            float sr[4];
#pragma unroll
            for (int r=0;r<4;r++) sr[r] = __shfl(scl, 20*g + r);
#pragma unroll
            for (int dq=0;dq<4;dq++){
                f32x4 a = accO[dq];
                a[0]*=sr[0]; a[1]*=sr[1]; a[2]*=sr[2]; a[3]*=sr[3];
                accO[dq] = a;
            }

            // ---- PV
            __builtin_amdgcn_s_setprio(1);
#pragma unroll
            for (int dq=0;dq<4;dq++)
                accO[dq] = MFMA(pa, vfr[sub][dq], accO[dq]);
            __builtin_amdgcn_s_setprio(0);
        }
    }
    #undef STAGE

    // ---- epilogue: O = acc / l (l for q=4g+r lives at lane 20g+r)
    float linv[4];
#pragma unroll
    for (int r=0;r<4;r++) linv[r] = 1.0f / __shfl(l_, 20*g + r);
#pragma unroll
    for (int dq=0;dq<4;dq++){
#pragma unroll
        for (int r=0;r<4;r++){
            const int t = t0 + 4*g + r;
            o[(size_t)(b*1024 + t)*768 + h*64 + 16*dq + cc] = accO[dq][r] * linv[r];
        }
    }
}

extern "C" void kernel_launch(void* const* d_in, const int* in_sizes, int n_in,
                              void* d_out, int out_size, void* d_ws, size_t ws_size,
                              hipStream_t stream) {
    const float* query = (const float*)d_in[0];
    const float* kdyn  = (const float*)d_in[1];
    const int*   kpm   = (const int*)d_in[2];
    const float* bias  = (const float*)d_in[3];
    const float* in_w  = (const float*)d_in[4];
    const float* in_b  = (const float*)d_in[5];
    const float* red_w = (const float*)d_in[6];
    const float* red_b = (const float*)d_in[7];
    const float* out_w = (const float*)d_in[8];
    const float* out_b = (const float*)d_in[9];
    float* out = (float*)d_out;

    const size_t SEG = (size_t)48*1024*64;
    unsigned short* qs = (unsigned short*)d_ws;
    unsigned short* kb = qs + SEG;
    unsigned short* vt = kb + SEG;
    float* o = (float*)(vt + SEG);                   // [4096][768] f32

    gemm_qkv<<<dim3(18,32), 256, 0, stream>>>(query, in_w, in_b, qs, kb, vt);
    attn_mfma<<<dim3(48,64), 64, 0, stream>>>(qs, kb, vt, kdyn, kpm, bias, red_w, red_b, o);
    gemm_mfma<<<dim3(6,32),  256, 0, stream>>>(o, out_w, out_b, out, 768, 768);
}

// Round 8
// 357.488 us; speedup vs baseline: 1.8418x; 1.8418x over previous
//
#include <hip/hip_runtime.h>
#include <math.h>

typedef __attribute__((ext_vector_type(8))) short s16x8;
typedef __attribute__((ext_vector_type(4))) float f32x4;

#define MFMA(a,b,c) __builtin_amdgcn_mfma_f32_16x16x32_bf16((a),(b),(c),0,0,0)

__device__ __forceinline__ unsigned short f2bf(float f){
    unsigned u = __builtin_bit_cast(unsigned, f);
    u += 0x7FFFu + ((u >> 16) & 1u);
    return (unsigned short)(u >> 16);
}
__device__ __forceinline__ float bf2f(unsigned short u){
    return __builtin_bit_cast(float, ((unsigned)u) << 16);
}
__device__ __forceinline__ float4 fma4(float s, float4 a, float4 c){
    c.x = fmaf(s, a.x, c.x); c.y = fmaf(s, a.y, c.y);
    c.z = fmaf(s, a.z, c.z); c.w = fmaf(s, a.w, c.w);
    return c;
}
__device__ __forceinline__ unsigned pk_bf16(float lo, float hi){
    return (unsigned)f2bf(lo) | ((unsigned)f2bf(hi) << 16);
}
__device__ __forceinline__ void gld_lds16(const void* g, void* l){
    __builtin_amdgcn_global_load_lds(
        (const __attribute__((address_space(1))) void*)g,
        (__attribute__((address_space(3))) void*)l, 16, 0, 0);
}

// ---------------------------------------------------------------------------
// QKV projection: qkv = query @ in_w^T + in_b, emitted as:
//   qs [48][1024][64] bf16  (q * 0.125)
//   kb [48][1024][64] bf16
//   vt [48][64][1024] bf16  (transposed)
// ---------------------------------------------------------------------------
__global__ __launch_bounds__(256) void gemm_qkv(
    const float* __restrict__ X, const float* __restrict__ W,
    const float* __restrict__ bvec,
    unsigned short* __restrict__ qs,
    unsigned short* __restrict__ kb,
    unsigned short* __restrict__ vtb)
{
    __shared__ __align__(16) unsigned short Al[128*64];
    __shared__ __align__(16) unsigned short Bl[128*64];
    const int tid = threadIdx.x;
    const int m0 = blockIdx.y*128, n0 = blockIdx.x*128;
    const int w = tid>>6, lane = tid&63, g = lane>>4, cc = lane&15;
    const int srow = tid>>1, kh = (tid&1)*32;
    const int arow_base = (w>>1)*64, brow_base = (w&1)*64;

    f32x4 acc[4][4];
#pragma unroll
    for (int i=0;i<4;i++)
#pragma unroll
        for (int j=0;j<4;j++) acc[i][j] = (f32x4){0.f,0.f,0.f,0.f};

    const float* xp = X + (size_t)(m0+srow)*768 + kh;
    const float* wp = W + (size_t)(n0+srow)*768 + kh;

    for (int kt = 0; kt < 768; kt += 64) {
        float4 xv[8], wv[8];
#pragma unroll
        for (int i=0;i<8;i++){
            xv[i] = *(const float4*)(xp + kt + i*4);
            wv[i] = *(const float4*)(wp + kt + i*4);
        }
        __syncthreads();
#pragma unroll
        for (int q=0;q<4;q++){
            alignas(16) unsigned short ta[8], tb[8];
            float4 a0=xv[2*q], a1=xv[2*q+1], b0=wv[2*q], b1=wv[2*q+1];
            ta[0]=f2bf(a0.x); ta[1]=f2bf(a0.y); ta[2]=f2bf(a0.z); ta[3]=f2bf(a0.w);
            ta[4]=f2bf(a1.x); ta[5]=f2bf(a1.y); ta[6]=f2bf(a1.z); ta[7]=f2bf(a1.w);
            tb[0]=f2bf(b0.x); tb[1]=f2bf(b0.y); tb[2]=f2bf(b0.z); tb[3]=f2bf(b0.w);
            tb[4]=f2bf(b1.x); tb[5]=f2bf(b1.y); tb[6]=f2bf(b1.z); tb[7]=f2bf(b1.w);
            const int gr = (kh>>3) + q;
            const int sw = ((gr ^ (srow&7))<<3);
            *(s16x8*)&Al[srow*64 + sw] = *(const s16x8*)ta;
            *(s16x8*)&Bl[srow*64 + sw] = *(const s16x8*)tb;
        }
        __syncthreads();
#pragma unroll
        for (int ks=0;ks<2;ks++){
            s16x8 af[4], bfr[4];
#pragma unroll
            for (int i=0;i<4;i++){
                const int ra = arow_base + i*16 + cc;
                const int rb = brow_base + i*16 + cc;
                af[i]  = *(const s16x8*)&Al[ra*64 + (((ks*4+g) ^ (ra&7))<<3)];
                bfr[i] = *(const s16x8*)&Bl[rb*64 + (((ks*4+g) ^ (rb&7))<<3)];
            }
#pragma unroll
            for (int i=0;i<4;i++)
#pragma unroll
                for (int j=0;j<4;j++)
                    acc[i][j] = MFMA(af[i], bfr[j], acc[i][j]);
        }
    }

    const int region = blockIdx.x / 6;   // 0:q 1:k 2:v
#pragma unroll
    for (int j=0;j<4;j++){
        const int n = n0 + brow_base + j*16 + cc;
        const float bb = bvec[n];
        const int nn = n - region*768;
        const int h = nn >> 6, d = nn & 63;
        if (region == 0){
#pragma unroll
            for (int i=0;i<4;i++){
                const int m = m0 + arow_base + i*16 + g*4;
                const int bq = m >> 10, t = m & 1023;
                unsigned short* dst = qs + ((size_t)(bq*12+h)*1024 + t)*64 + d;
#pragma unroll
                for (int r=0;r<4;r++)
                    dst[(size_t)r*64] = f2bf((acc[i][j][r] + bb)*0.125f);
            }
        } else if (region == 1){
#pragma unroll
            for (int i=0;i<4;i++){
                const int m = m0 + arow_base + i*16 + g*4;
                const int bq = m >> 10, t = m & 1023;
                unsigned short* dst = kb + ((size_t)(bq*12+h)*1024 + t)*64 + d;
#pragma unroll
                for (int r=0;r<4;r++)
                    dst[(size_t)r*64] = f2bf(acc[i][j][r] + bb);
            }
        } else {
#pragma unroll
            for (int i=0;i<4;i++){
                const int m = m0 + arow_base + i*16 + g*4;
                const int bq = m >> 10, t = m & 1023;
                ushort4 pk;
                pk.x = f2bf(acc[i][j][0] + bb);
                pk.y = f2bf(acc[i][j][1] + bb);
                pk.z = f2bf(acc[i][j][2] + bb);
                pk.w = f2bf(acc[i][j][3] + bb);
                *(ushort4*)&vtb[((size_t)(bq*12+h)*64 + d)*1024 + t] = pk;
            }
        }
    }
}

// ---------------------------------------------------------------------------
// Generic x @ W^T + b (f32 in/out) for the output projection.
// ---------------------------------------------------------------------------
__global__ __launch_bounds__(256) void gemm_mfma(
    const float* __restrict__ X, const float* __restrict__ W,
    const float* __restrict__ bvec, float* __restrict__ out,
    int N, int K)
{
    __shared__ __align__(16) unsigned short Al[128*64];
    __shared__ __align__(16) unsigned short Bl[128*64];
    const int tid = threadIdx.x;
    const int m0 = blockIdx.y*128, n0 = blockIdx.x*128;
    const int w = tid>>6, lane = tid&63, g = lane>>4, cc = lane&15;
    const int srow = tid>>1, kh = (tid&1)*32;
    const int arow_base = (w>>1)*64, brow_base = (w&1)*64;

    f32x4 acc[4][4];
#pragma unroll
    for (int i=0;i<4;i++)
#pragma unroll
        for (int j=0;j<4;j++) acc[i][j] = (f32x4){0.f,0.f,0.f,0.f};

    const float* xp = X + (size_t)(m0+srow)*K + kh;
    const float* wp = W + (size_t)(n0+srow)*K + kh;

    for (int kt = 0; kt < K; kt += 64) {
        float4 xv[8], wv[8];
#pragma unroll
        for (int i=0;i<8;i++){
            xv[i] = *(const float4*)(xp + kt + i*4);
            wv[i] = *(const float4*)(wp + kt + i*4);
        }
        __syncthreads();
#pragma unroll
        for (int q=0;q<4;q++){
            alignas(16) unsigned short ta[8], tb[8];
            float4 a0=xv[2*q], a1=xv[2*q+1], b0=wv[2*q], b1=wv[2*q+1];
            ta[0]=f2bf(a0.x); ta[1]=f2bf(a0.y); ta[2]=f2bf(a0.z); ta[3]=f2bf(a0.w);
            ta[4]=f2bf(a1.x); ta[5]=f2bf(a1.y); ta[6]=f2bf(a1.z); ta[7]=f2bf(a1.w);
            tb[0]=f2bf(b0.x); tb[1]=f2bf(b0.y); tb[2]=f2bf(b0.z); tb[3]=f2bf(b0.w);
            tb[4]=f2bf(b1.x); tb[5]=f2bf(b1.y); tb[6]=f2bf(b1.z); tb[7]=f2bf(b1.w);
            const int gr = (kh>>3) + q;
            const int sw = ((gr ^ (srow&7))<<3);
            *(s16x8*)&Al[srow*64 + sw] = *(const s16x8*)ta;
            *(s16x8*)&Bl[srow*64 + sw] = *(const s16x8*)tb;
        }
        __syncthreads();
#pragma unroll
        for (int ks=0;ks<2;ks++){
            s16x8 af[4], bfr[4];
#pragma unroll
            for (int i=0;i<4;i++){
                const int ra = arow_base + i*16 + cc;
                const int rb = brow_base + i*16 + cc;
                af[i]  = *(const s16x8*)&Al[ra*64 + (((ks*4+g) ^ (ra&7))<<3)];
                bfr[i] = *(const s16x8*)&Bl[rb*64 + (((ks*4+g) ^ (rb&7))<<3)];
            }
#pragma unroll
            for (int i=0;i<4;i++)
#pragma unroll
                for (int j=0;j<4;j++)
                    acc[i][j] = MFMA(af[i], bfr[j], acc[i][j]);
        }
    }
#pragma unroll
    for (int j=0;j<4;j++){
        const int n = n0 + brow_base + j*16 + cc;
        const float bb = bvec[n];
#pragma unroll
        for (int i=0;i<4;i++){
            const int mb = m0 + arow_base + i*16 + g*4;
#pragma unroll
            for (int r=0;r<4;r++)
                out[(size_t)(mb+r)*N + n] = acc[i][j][r] + bb;
        }
    }
}

// ---------------------------------------------------------------------------
// Flash attention, 1 wave / 16 q-rows per block. s-chunk = 128.
// kdyn+bias staged via global_load_lds (512 B contiguous per (t,r) row visit),
// SINGLE-buffered 40 KB LDS -> 4 blocks/CU (4 independent waves, no barriers,
// natural cross-wave transfer/compute staggering). K/V/mask read directly
// from L2 at use time. Per chunk: 40 DMA -> vmcnt(0) -> compute 4 subs.
// ---------------------------------------------------------------------------
__global__ __launch_bounds__(64, 1) void attn_mfma(
    const unsigned short* __restrict__ qs,   // [48][1024][64] bf16 (q*0.125)
    const unsigned short* __restrict__ kbf,  // [48][1024][64] bf16
    const unsigned short* __restrict__ vtf,  // [48][64][1024] bf16
    const float* __restrict__ kdyn,          // [48*1024][4][1024]
    const int*   __restrict__ kpm,           // [4][1024]
    const float* __restrict__ bias,          // [48][1024][1024]
    const float* __restrict__ red_w,         // [4][64]
    const float* __restrict__ red_b,         // [4]
    float* __restrict__ o)                   // [4096][768]
{
    __shared__ __align__(16) float kdL[8192];   // 32 KB: row rr=t*4+r, 128 f32
    __shared__ __align__(16) float bL[2048];    //  8 KB: row t, 128 f32

    const int lane = threadIdx.x & 63;
    const int bh = blockIdx.x, qt = blockIdx.y;   // bh fastest: same-bh -> same XCD
    const int b = bh / 12, h = bh % 12;
    const int t0 = qt*16;
    const int g = lane>>4, cc = lane&15;
    const int tq = t0 + cc;                        // lane's q row (within b,h)

    // ---- Q fragments (B-operand): Q[q=cc][d = 32ks+8g+e]
    const unsigned short* qrow = qs + ((size_t)bh*1024 + tq)*64;
    s16x8 qf[2];
    qf[0] = *(const s16x8*)(qrow + g*8);
    qf[1] = *(const s16x8*)(qrow + 32 + g*8);

    // ---- qred[r] for q=cc
    float qred[4];
    {
        float pr[4] = {0.f,0.f,0.f,0.f};
#pragma unroll
        for (int ks=0; ks<2; ks++){
#pragma unroll
            for (int r=0;r<4;r++){
                float4 w0 = *(const float4*)(red_w + r*64 + 32*ks + 8*g);
                float4 w1 = *(const float4*)(red_w + r*64 + 32*ks + 8*g + 4);
                pr[r] += bf2f((unsigned short)qf[ks][0])*w0.x + bf2f((unsigned short)qf[ks][1])*w0.y
                       + bf2f((unsigned short)qf[ks][2])*w0.z + bf2f((unsigned short)qf[ks][3])*w0.w
                       + bf2f((unsigned short)qf[ks][4])*w1.x + bf2f((unsigned short)qf[ks][5])*w1.y
                       + bf2f((unsigned short)qf[ks][6])*w1.z + bf2f((unsigned short)qf[ks][7])*w1.w;
            }
        }
#pragma unroll
        for (int r=0;r<4;r++){
            pr[r] += __shfl_xor(pr[r], 16);
            pr[r] += __shfl_xor(pr[r], 32);
            qred[r] = pr[r]*8.f + red_b[r];
        }
    }

    f32x4 accO[4];
#pragma unroll
    for (int i=0;i<4;i++) accO[i] = (f32x4){0.f,0.f,0.f,0.f};
    float m_ = -1e30f, l_ = 0.f;

    const unsigned short* kcb = kbf + (size_t)bh*1024*64;
    const unsigned short* vcb = vtf + ((size_t)bh*64 + cc)*1024;
    const int* mp = kpm + b*1024 + 4*g;
    const size_t kd_row = (size_t)(bh*1024 + t0);

    // staging lane geometry: 2 rows per DMA inst, 32 granules (16 B) per row
    const int half = lane>>5, gl = lane&31;

    #define STAGE(c_) do {                                                        \
        const int s0_ = (c_)*128;                                                 \
        _Pragma("unroll")                                                         \
        for (int i_=0;i_<32;i_++){            /* kdyn: rows rr=2i+half */         \
            const int rr_ = 2*i_ + half;                                          \
            const int t_ = rr_>>2, r_ = rr_&3;                                    \
            const int gsw_ = (gl & 24) | ((gl&7) ^ (t_&7));                       \
            gld_lds16(kdyn + (kd_row + t_)*4096 + (size_t)r_*1024 + s0_ + gsw_*4, \
                      &kdL[i_*256]);                                              \
        }                                                                         \
        _Pragma("unroll")                                                         \
        for (int i_=0;i_<8;i_++){             /* bias: rows t=2i+half */          \
            const int t_ = 2*i_ + half;                                           \
            const int gsw_ = (gl & 24) | ((gl&7) ^ (t_&7));                       \
            gld_lds16(bias + (kd_row + t_)*1024 + s0_ + gsw_*4,                   \
                      &bL[i_*256]);                                               \
        }                                                                         \
    } while(0)

    // ---- prologue: stage chunk 0
    STAGE(0);

    const float NINF = -__builtin_inff();
    const int srcA = ((g&1)<<5) + cc;
    const int srcB = srcA + 16;
    const bool hi_half = (g>>1) != 0;

#pragma unroll 1
    for (int c = 0; c < 8; ++c) {
        const int cbase = c*128;

        // ---- wait for this chunk's staging (single buffer)
        asm volatile("s_waitcnt vmcnt(0)" ::: "memory");
        __builtin_amdgcn_sched_barrier(0);

#pragma unroll
        for (int sub=0;sub<4;sub++){
            const int s32 = cbase + sub*32;

            // ---- use-time L2 register loads: K, V, mask
            s16x8 kfr[2][2];
#pragma unroll
            for (int sq=0;sq<2;sq++){
                const unsigned short* kp = kcb + (size_t)(s32 + 16*sq + cc)*64 + g*8;
                kfr[sq][0] = *(const s16x8*)(kp);
                kfr[sq][1] = *(const s16x8*)(kp + 32);
            }
            s16x8 vfr[4];
#pragma unroll
            for (int dq=0;dq<4;dq++)
                vfr[dq] = *(const s16x8*)(vcb + (size_t)dq*16*1024 + s32 + 8*g);
            int4 mm0 = *(const int4*)(mp + s32);
            int4 mm1 = *(const int4*)(mp + s32 + 16);

            // ---- dyn tile from LDS (swizzled read): t=cc, s=16sq+4g+{0..3}
            float4 dyn[2];
#pragma unroll
            for (int sq=0;sq<2;sq++){
                const int slot = (sub*8 + ((4*sq + g) ^ (cc&7))) << 2;
                float4 dv = *(const float4*)&bL[cc*128 + slot];
                dv = fma4(qred[0], *(const float4*)&kdL[(cc*4+0)*128 + slot], dv);
                dv = fma4(qred[1], *(const float4*)&kdL[(cc*4+1)*128 + slot], dv);
                dv = fma4(qred[2], *(const float4*)&kdL[(cc*4+2)*128 + slot], dv);
                dv = fma4(qred[3], *(const float4*)&kdL[(cc*4+3)*128 + slot], dv);
                const int4 m4 = sq ? mm1 : mm0;
                dv.x = m4.x ? NINF : dv.x;
                dv.y = m4.y ? NINF : dv.y;
                dv.z = m4.z ? NINF : dv.z;
                dv.w = m4.w ? NINF : dv.w;
                dyn[sq] = dv;
            }

            // ---- QK^T (swapped): D[s_local=16sq+4g+r][q=cc]
            f32x4 sc[2];
            __builtin_amdgcn_s_setprio(1);
#pragma unroll
            for (int sq=0;sq<2;sq++){
                f32x4 z = (f32x4){0.f,0.f,0.f,0.f};
                z = MFMA(kfr[sq][0], qf[0], z);
                z = MFMA(kfr[sq][1], qf[1], z);
                sc[sq] = z;
            }
            __builtin_amdgcn_s_setprio(0);

            // ---- softmax (in-register; q=cc shared by 4 g-lanes)
            float v[8];
#pragma unroll
            for (int sq=0;sq<2;sq++){
                v[sq*4+0] = sc[sq][0] + dyn[sq].x;
                v[sq*4+1] = sc[sq][1] + dyn[sq].y;
                v[sq*4+2] = sc[sq][2] + dyn[sq].z;
                v[sq*4+3] = sc[sq][3] + dyn[sq].w;
            }
            float mx = v[0];
#pragma unroll
            for (int i=1;i<8;i++) mx = fmaxf(mx, v[i]);
            mx = fmaxf(mx, __shfl_xor(mx, 16));
            mx = fmaxf(mx, __shfl_xor(mx, 32));
            const float mn = fmaxf(m_, mx);
            float ps = 0.f;
#pragma unroll
            for (int i=0;i<8;i++){ v[i] = __expf(v[i]-mn); ps += v[i]; }
            ps += __shfl_xor(ps, 16);
            ps += __shfl_xor(ps, 32);
            const float scl = __expf(m_-mn);
            m_ = mn; l_ = l_*scl + ps;

            // ---- pack P, exchange -> PV A-fragment P[q=cc][s=8g+e]
            unsigned U[4] = { pk_bf16(v[0],v[1]), pk_bf16(v[2],v[3]),
                              pk_bf16(v[4],v[5]), pk_bf16(v[6],v[7]) };
            unsigned a0 = (unsigned)__shfl((int)U[0], srcA);
            unsigned a1 = (unsigned)__shfl((int)U[1], srcA);
            unsigned a2 = (unsigned)__shfl((int)U[2], srcA);
            unsigned a3 = (unsigned)__shfl((int)U[3], srcA);
            unsigned b0 = (unsigned)__shfl((int)U[0], srcB);
            unsigned b1 = (unsigned)__shfl((int)U[1], srcB);
            unsigned b2 = (unsigned)__shfl((int)U[2], srcB);
            unsigned b3 = (unsigned)__shfl((int)U[3], srcB);
            alignas(16) unsigned wv4[4] = { hi_half ? a2 : a0, hi_half ? a3 : a1,
                                            hi_half ? b2 : b0, hi_half ? b3 : b1 };
            s16x8 pa = *(const s16x8*)wv4;

            // ---- rescale accO (scl for q=4g+r lives at lane 20g+r)
            float sr[4];
#pragma unroll
            for (int r=0;r<4;r++) sr[r] = __shfl(scl, 20*g + r);
#pragma unroll
            for (int dq=0;dq<4;dq++){
                f32x4 a = accO[dq];
                a[0]*=sr[0]; a[1]*=sr[1]; a[2]*=sr[2]; a[3]*=sr[3];
                accO[dq] = a;
            }

            // ---- PV
            __builtin_amdgcn_s_setprio(1);
#pragma unroll
            for (int dq=0;dq<4;dq++)
                accO[dq] = MFMA(pa, vfr[dq], accO[dq]);
            __builtin_amdgcn_s_setprio(0);
        }

        // ---- stage next chunk (after all LDS reads of this chunk are consumed)
        if (c < 7) STAGE(c+1);
    }
    #undef STAGE

    // ---- epilogue: O = acc / l (l for q=4g+r lives at lane 20g+r)
    float linv[4];
#pragma unroll
    for (int r=0;r<4;r++) linv[r] = 1.0f / __shfl(l_, 20*g + r);
#pragma unroll
    for (int dq=0;dq<4;dq++){
#pragma unroll
        for (int r=0;r<4;r++){
            const int t = t0 + 4*g + r;
            o[(size_t)(b*1024 + t)*768 + h*64 + 16*dq + cc] = accO[dq][r] * linv[r];
        }
    }
}

extern "C" void kernel_launch(void* const* d_in, const int* in_sizes, int n_in,
                              void* d_out, int out_size, void* d_ws, size_t ws_size,
                              hipStream_t stream) {
    const float* query = (const float*)d_in[0];
    const float* kdyn  = (const float*)d_in[1];
    const int*   kpm   = (const int*)d_in[2];
    const float* bias  = (const float*)d_in[3];
    const float* in_w  = (const float*)d_in[4];
    const float* in_b  = (const float*)d_in[5];
    const float* red_w = (const float*)d_in[6];
    const float* red_b = (const float*)d_in[7];
    const float* out_w = (const float*)d_in[8];
    const float* out_b = (const float*)d_in[9];
    float* out = (float*)d_out;

    const size_t SEG = (size_t)48*1024*64;
    unsigned short* qs = (unsigned short*)d_ws;
    unsigned short* kb = qs + SEG;
    unsigned short* vt = kb + SEG;
    float* o = (float*)(vt + SEG);                   // [4096][768] f32

    gemm_qkv<<<dim3(18,32), 256, 0, stream>>>(query, in_w, in_b, qs, kb, vt);
    attn_mfma<<<dim3(48,64), 64, 0, stream>>>(qs, kb, vt, kdyn, kpm, bias, red_w, red_b, o);
    gemm_mfma<<<dim3(6,32),  256, 0, stream>>>(o, out_w, out_b, out, 768, 768);
}